// Round 6
// baseline (499.808 us; speedup 1.0000x reference)
//
#include <hip/hip_runtime.h>
#include <hip/hip_bf16.h>

#define N_NODES 50000
#define N_EDGES 250000
#define DIM 32

// flags[0..7]: 1 if float input j is fp32, 0 if bf16 (via atomicOr on pre-zeroed).
//   order: x, ea, node_W, node_b, l1_W, l1_b, root, conv_b
// flags[8]: 1 if any odd int32 word of ei[0..127] is nonzero => ei is int32.
//           (int64 LE with values < 2^31 has all odd words zero.)
// 9 blocks x 64 lanes; block-uniform buffer choice; no ballot, no local arrays.
__global__ __launch_bounds__(64) void detect_kernel(
    const void* x, const void* ea, const void* nW, const void* nb,
    const void* lW, const void* lb, const void* rt, const void* cb,
    const int* __restrict__ ei, int* __restrict__ flags)
{
    int lane = threadIdx.x;   // 0..63
    int b = blockIdx.x;       // 0..8
    if (b == 8) {
        if (ei[2 * lane + 1] != 0) atomicOr(&flags[8], 1);
        return;
    }
    const unsigned short* hs;
    int K;   // halves to inspect; K*2 bytes <= bf16 buffer size
    switch (b) {
        case 0:  hs = (const unsigned short*)x;  K = 128; break;
        case 1:  hs = (const unsigned short*)ea; K = 128; break;
        case 2:  hs = (const unsigned short*)nW; K = 32;  break;
        case 3:  hs = (const unsigned short*)nb; K = 32;  break;
        case 4:  hs = (const unsigned short*)lW; K = 128; break;
        case 5:  hs = (const unsigned short*)lb; K = 128; break;
        case 6:  hs = (const unsigned short*)rt; K = 128; break;
        default: hs = (const unsigned short*)cb; K = 32;  break;
    }
    int bad = 0;
    for (int k = lane; k < K; k += 64) {
        float v = __uint_as_float(((unsigned int)hs[k]) << 16);  // decode as bf16
        if (!(fabsf(v) <= 50.0f)) bad = 1;   // huge or NaN -> fp32 buffer
    }
    if (bad) atomicOr(&flags[b], 1);
}

__device__ __forceinline__ float ldf(const void* p, int i, int isf32) {
    return isf32 ? ((const float*)p)[i]
                 : __bfloat162float(((const __hip_bfloat16*)p)[i]);
}
__device__ __forceinline__ int ldi(const int* __restrict__ ei, int i, int i64) {
    return i64 ? ei[2 * i] : ei[i];
}
__device__ __forceinline__ int clamp_idx(int v) {
    v = v < 0 ? 0 : v;
    return v >= N_NODES ? N_NODES - 1 : v;
}

// --- once per call: compact indices to int2, ea to fp32, in-degree count ---
__global__ __launch_bounds__(256) void prep_kernel(
    const int* __restrict__ ei, const void* __restrict__ ea,
    const int* __restrict__ flags,
    int2* __restrict__ eid, float* __restrict__ eaf, float* __restrict__ cnt)
{
    int e = blockIdx.x * 256 + threadIdx.x;
    if (e >= N_EDGES) return;
    int i64 = (flags[8] == 0);
    int s = clamp_idx(ldi(ei, e, i64));
    int d = clamp_idx(ldi(ei, N_EDGES + e, i64));
    eid[e] = make_int2(s, d);
    eaf[e] = ldf(ea, e, flags[1]);
    atomicAdd(&cnt[d], 1.0f);
}

// --- fused layer head: h = (mode0: x@nW+nb) | (mode1: aggr/c + conv_b);
//     hr = relu(h); u = hr@L1W, v = hr@L1B, aggr = c*(hr@root)  [seed]
// block = 256 = 8 nodes x 32 lanes; 3x 32x32 fp32 weights in LDS. ---
__global__ __launch_bounds__(256) void gemm3_kernel(
    const void* __restrict__ x, const void* __restrict__ node_W,
    const void* __restrict__ node_b, const void* __restrict__ conv_b,
    const void* __restrict__ l1_W, const void* __restrict__ l1_b,
    const void* __restrict__ root,
    const int* __restrict__ flags, const float* __restrict__ cnt, int mode,
    float* __restrict__ u, float* __restrict__ v, float* __restrict__ aggr)
{
    __shared__ float sW[DIM * DIM];
    __shared__ float sB[DIM * DIM];
    __shared__ float sR[DIM * DIM];
    __shared__ float sh[8][DIM + 1];

    int tid = threadIdx.x;
    int fW = flags[4], fB = flags[5], fR = flags[6];
    for (int k = tid; k < DIM * DIM; k += 256) {
        sW[k] = ldf(l1_W, k, fW);
        sB[k] = ldf(l1_b, k, fB);
        sR[k] = ldf(root, k, fR);
    }
    int local = tid >> 5;   // 0..7
    int lane  = tid & 31;   // 0..31
    int n = blockIdx.x * 8 + local;
    float c = 1.0f;
    if (n < N_NODES) {
        c = cnt[n];
        c = c < 1.0f ? 1.0f : c;
        float hv;
        if (mode == 0)
            hv = fmaf(ldf(x, n, flags[0]), ldf(node_W, lane, flags[2]),
                      ldf(node_b, lane, flags[3]));
        else
            hv = aggr[n * DIM + lane] / c + ldf(conv_b, lane, flags[7]);
        sh[local][lane] = hv > 0.0f ? hv : 0.0f;   // relu
    }
    __syncthreads();
    if (n >= N_NODES) return;

    float au = 0.0f, av = 0.0f, ar = 0.0f;
    #pragma unroll
    for (int i = 0; i < DIM; ++i) {
        float hv = sh[local][i];                   // LDS broadcast
        au = fmaf(hv, sW[i * DIM + lane], au);     // conflict-free
        av = fmaf(hv, sB[i * DIM + lane], av);
        ar = fmaf(hv, sR[i * DIM + lane], ar);
    }
    u[n * DIM + lane] = au;
    v[n * DIM + lane] = av;
    aggr[n * DIM + lane] = c * ar;   // (sum_msg + c*r)/c == sum/c + r
}

// --- edge scatter: aggr[dst] += ea*u[src] + v[src]; 8 lanes x float4/edge ---
__global__ __launch_bounds__(256) void edge_kernel(
    const int2* __restrict__ eid, const float* __restrict__ eaf,
    const float4* __restrict__ u4, const float4* __restrict__ v4,
    float* __restrict__ aggr)
{
    int t = blockIdx.x * 256 + threadIdx.x;
    int e = t >> 3;
    if (e >= N_EDGES) return;
    int sub = t & 7;
    int2 sd = eid[e];
    float a = eaf[e];
    float4 uu = u4[sd.x * 8 + sub];
    float4 vv = v4[sd.x * 8 + sub];
    float* base = aggr + sd.y * DIM + sub * 4;
    atomicAdd(base + 0, fmaf(a, uu.x, vv.x));
    atomicAdd(base + 1, fmaf(a, uu.y, vv.y));
    atomicAdd(base + 2, fmaf(a, uu.z, vv.z));
    atomicAdd(base + 3, fmaf(a, uu.w, vv.w));
}

// --- final: out = aggr/c + conv_b (fp32 out) ---
__global__ __launch_bounds__(256) void finalize_kernel(
    const float* __restrict__ aggr, const float* __restrict__ cnt,
    const void* __restrict__ conv_b, const int* __restrict__ flags,
    float* __restrict__ out)
{
    int t = blockIdx.x * 256 + threadIdx.x;
    if (t >= N_NODES * DIM) return;
    int n = t >> 5;
    int d = t & 31;
    float c = cnt[n];
    c = c < 1.0f ? 1.0f : c;
    out[t] = aggr[t] / c + ldf(conv_b, d, flags[7]);
}

extern "C" void kernel_launch(void* const* d_in, const int* in_sizes, int n_in,
                              void* d_out, int out_size, void* d_ws, size_t ws_size,
                              hipStream_t stream) {
    // Locate inputs by size pattern (skip scalar args):
    // 50000(x), 500000(edge_index), 250000(ea), 32(node_W), 32(node_b),
    // 1024(l1_W), 1024(l1_b), 1024(root), 32(conv_b)
    const void* p[16];
    int np_ = 0;
    for (int i = 0; i < n_in && np_ < 16; ++i)
        if (in_sizes[i] != 1) p[np_++] = d_in[i];

    const void* x      = p[0];
    const int*  ei     = (const int*)p[1];
    const void* ea     = p[2];
    const void* node_W = p[3];
    const void* node_b = p[4];
    const void* l1_W   = p[5];
    const void* l1_b   = p[6];
    const void* root   = p[7];
    const void* conv_b = p[8];
    float* out = (float*)d_out;

    const int ND = N_NODES * DIM;
    float* ws    = (float*)d_ws;
    int2*  eid   = (int2*)ws;                 // E int2 (2,000,000 B; 16B-aligned)
    float* u     = ws + 2 * N_EDGES;          // N*D
    float* v     = u + ND;                    // N*D
    float* aggr  = v + ND;                    // N*D
    float* cnt   = aggr + ND;                 // N
    float* eaf   = cnt + N_NODES;             // E
    int*   flags = (int*)(eaf + N_EDGES);     // 9 ints

    hipMemsetAsync(flags, 0, 9 * sizeof(int), stream);
    hipMemsetAsync(cnt, 0, N_NODES * sizeof(float), stream);
    detect_kernel<<<9, 64, 0, stream>>>(x, ea, node_W, node_b, l1_W, l1_b,
                                        root, conv_b, ei, flags);
    prep_kernel<<<(N_EDGES + 255) / 256, 256, 0, stream>>>(ei, ea, flags,
                                                           eid, eaf, cnt);

    const int gemm_blocks = (N_NODES + 7) / 8;               // 6250
    const int edge_blocks = (N_EDGES * 8 + 255) / 256;       // 7813
    const int nd_blocks   = (ND + 255) / 256;                // 6250

    for (int layer = 0; layer < 3; ++layer) {
        gemm3_kernel<<<gemm_blocks, 256, 0, stream>>>(
            x, node_W, node_b, conv_b, l1_W, l1_b, root, flags, cnt,
            layer == 0 ? 0 : 1, u, v, aggr);
        edge_kernel<<<edge_blocks, 256, 0, stream>>>(eid, eaf, (const float4*)u,
                                                     (const float4*)v, aggr);
    }
    finalize_kernel<<<nd_blocks, 256, 0, stream>>>(aggr, cnt, conv_b, flags, out);
}

// Round 8
// 265.636 us; speedup vs baseline: 1.8816x; 1.8816x over previous
//
#include <hip/hip_runtime.h>
#include <hip/hip_bf16.h>

#define N_NODES 50000
#define N_EDGES 250000
#define DIM 32
#define SCAN_B 1024
#define SCAN_NB ((N_NODES + SCAN_B - 1) / SCAN_B)   /* 49 */

// flags[0..7]: 1 if float input j is fp32, 0 if bf16 (atomicOr on pre-zeroed).
// order: x, ea, node_W, node_b, l1_W, l1_b, root, conv_b
// flags[8]: 1 if any odd int32 word of ei[0..127] nonzero, meaning ei is int32.
__global__ __launch_bounds__(64) void detect_kernel(
    const void* x, const void* ea, const void* nW, const void* nb,
    const void* lW, const void* lb, const void* rt, const void* cb,
    const int* __restrict__ ei, int* __restrict__ flags)
{
    int lane = threadIdx.x;
    int b = blockIdx.x;
    if (b == 8) {
        if (ei[2 * lane + 1] != 0) atomicOr(&flags[8], 1);
        return;
    }
    const unsigned short* hs;
    int K;
    switch (b) {
        case 0:  hs = (const unsigned short*)x;  K = 128; break;
        case 1:  hs = (const unsigned short*)ea; K = 128; break;
        case 2:  hs = (const unsigned short*)nW; K = 32;  break;
        case 3:  hs = (const unsigned short*)nb; K = 32;  break;
        case 4:  hs = (const unsigned short*)lW; K = 128; break;
        case 5:  hs = (const unsigned short*)lb; K = 128; break;
        case 6:  hs = (const unsigned short*)rt; K = 128; break;
        default: hs = (const unsigned short*)cb; K = 32;  break;
    }
    int bad = 0;
    for (int k = lane; k < K; k += 64) {
        float v = __uint_as_float(((unsigned int)hs[k]) << 16);
        if (!(fabsf(v) <= 50.0f)) bad = 1;
    }
    if (bad) atomicOr(&flags[b], 1);
}

__device__ __forceinline__ float ldf(const void* p, int i, int isf32) {
    return isf32 ? ((const float*)p)[i]
                 : __bfloat162float(((const __hip_bfloat16*)p)[i]);
}
__device__ __forceinline__ int ldi(const int* __restrict__ ei, int i, int i64) {
    return i64 ? ei[2 * i] : ei[i];
}
__device__ __forceinline__ int clamp_idx(int v) {
    v = v < 0 ? 0 : v;
    return v >= N_NODES ? N_NODES - 1 : v;
}

// prep 1: decode edges, count in-degrees
__global__ __launch_bounds__(256) void count_kernel(
    const int* __restrict__ ei, const void* __restrict__ ea,
    const int* __restrict__ flags,
    int2* __restrict__ eid, float* __restrict__ eaf, int* __restrict__ cntI)
{
    int e = blockIdx.x * 256 + threadIdx.x;
    if (e >= N_EDGES) return;
    int i64 = (flags[8] == 0);
    int s = clamp_idx(ldi(ei, e, i64));
    int d = clamp_idx(ldi(ei, N_EDGES + e, i64));
    eid[e] = make_int2(s, d);
    eaf[e] = ldf(ea, e, flags[1]);
    atomicAdd(&cntI[d], 1);
}

// prep 2a: per-block exclusive scan of cntI into rowstart, plus block sums
__global__ __launch_bounds__(SCAN_B) void scan_local_kernel(
    const int* __restrict__ cntI, int* __restrict__ rowstart, int* __restrict__ bsum)
{
    __shared__ int b0[SCAN_B], b1[SCAN_B];
    int t = threadIdx.x;
    int g = blockIdx.x * SCAN_B + t;
    int v = (g < N_NODES) ? cntI[g] : 0;
    b0[t] = v;
    __syncthreads();
    int* src = b0; int* dst = b1;
    for (int off = 1; off < SCAN_B; off <<= 1) {
        int xv = src[t];
        if (t >= off) xv += src[t - off];
        dst[t] = xv;
        __syncthreads();
        int* tmp = src; src = dst; dst = tmp;
    }
    int incl = src[t];
    if (g < N_NODES) rowstart[g] = incl - v;
    if (t == SCAN_B - 1) bsum[blockIdx.x] = incl;
}

// prep 2b: exclusive scan of the 49 block sums, in place
__global__ __launch_bounds__(64) void scan_bsum_kernel(int* __restrict__ bsum)
{
    __shared__ int sb[64];
    int t = threadIdx.x;
    int v = (t < SCAN_NB) ? bsum[t] : 0;
    sb[t] = v;
    __syncthreads();
    for (int off = 1; off < 64; off <<= 1) {
        int xv = sb[t];
        if (t >= off) xv += sb[t - off];
        __syncthreads();
        sb[t] = xv;
        __syncthreads();
    }
    if (t < SCAN_NB) bsum[t] = sb[t] - v;
}

// prep 2c: add block offsets
__global__ __launch_bounds__(SCAN_B) void scan_add_kernel(
    int* __restrict__ rowstart, const int* __restrict__ bsum)
{
    int g = blockIdx.x * SCAN_B + threadIdx.x;
    if (g < N_NODES) rowstart[g] += bsum[blockIdx.x];
}

// prep 3: scatter edges into CSR buckets; packed[slot] = (src, bits(a))
__global__ __launch_bounds__(256) void scatter_kernel(
    const int2* __restrict__ eid, const float* __restrict__ eaf,
    const int* __restrict__ rowstart, int* __restrict__ edge_cur,
    int2* __restrict__ packed)
{
    int e = blockIdx.x * 256 + threadIdx.x;
    if (e >= N_EDGES) return;
    int2 sd = eid[e];
    int slot = rowstart[sd.y] + atomicAdd(&edge_cur[sd.y], 1);
    packed[slot] = make_int2(sd.x, __float_as_int(eaf[e]));
}

// fused layer head: h = (mode0: x@nW+nb) or (mode1: aggr/c + conv_b);
// hr = relu(h); uv row = (hr@L1W, hr@L1B) interleaved float2;
// aggr seeded with c*(hr@root). block 256 = 8 nodes x 32 lanes.
__global__ __launch_bounds__(256) void gemm3_kernel(
    const void* __restrict__ x, const void* __restrict__ node_W,
    const void* __restrict__ node_b, const void* __restrict__ conv_b,
    const void* __restrict__ l1_W, const void* __restrict__ l1_b,
    const void* __restrict__ root,
    const int* __restrict__ flags, const int* __restrict__ cntI, int mode,
    float2* __restrict__ uv, float* __restrict__ aggr)
{
    __shared__ float sW[DIM * DIM];
    __shared__ float sB[DIM * DIM];
    __shared__ float sR[DIM * DIM];
    __shared__ float sh[8][DIM + 1];

    int tid = threadIdx.x;
    int fW = flags[4], fB = flags[5], fR = flags[6];
    for (int k = tid; k < DIM * DIM; k += 256) {
        sW[k] = ldf(l1_W, k, fW);
        sB[k] = ldf(l1_b, k, fB);
        sR[k] = ldf(root, k, fR);
    }
    int local = tid >> 5;
    int lane  = tid & 31;
    int n = blockIdx.x * 8 + local;
    float c = 1.0f;
    if (n < N_NODES) {
        int ci = cntI[n];
        c = ci < 1 ? 1.0f : (float)ci;
        float hv;
        if (mode == 0)
            hv = fmaf(ldf(x, n, flags[0]), ldf(node_W, lane, flags[2]),
                      ldf(node_b, lane, flags[3]));
        else
            hv = aggr[n * DIM + lane] / c + ldf(conv_b, lane, flags[7]);
        sh[local][lane] = hv > 0.0f ? hv : 0.0f;
    }
    __syncthreads();
    if (n >= N_NODES) return;

    float au = 0.0f, av = 0.0f, ar = 0.0f;
    #pragma unroll
    for (int i = 0; i < DIM; ++i) {
        float hv = sh[local][i];
        au = fmaf(hv, sW[i * DIM + lane], au);
        av = fmaf(hv, sB[i * DIM + lane], av);
        ar = fmaf(hv, sR[i * DIM + lane], ar);
    }
    uv[n * DIM + lane] = make_float2(au, av);
    aggr[n * DIM + lane] = c * ar;
}

// gather aggregation, no atomics: 32 lanes own node n's row
__global__ __launch_bounds__(256) void gather_kernel(
    const int2* __restrict__ packed, const int* __restrict__ rowstart,
    const int* __restrict__ cntI, const float2* __restrict__ uv,
    float* __restrict__ aggr)
{
    int tid = threadIdx.x;
    int n = blockIdx.x * 8 + (tid >> 5);
    if (n >= N_NODES) return;
    int lane = tid & 31;
    int start = rowstart[n];
    int end = start + cntI[n];
    float acc = aggr[n * DIM + lane];
    for (int k = start; k < end; ++k) {
        int2 sa = packed[k];
        float a = __int_as_float(sa.y);
        float2 f = uv[sa.x * DIM + lane];
        acc += fmaf(a, f.x, f.y);
    }
    aggr[n * DIM + lane] = acc;
}

// final: out = aggr/c + conv_b (fp32 out)
__global__ __launch_bounds__(256) void finalize_kernel(
    const float* __restrict__ aggr, const int* __restrict__ cntI,
    const void* __restrict__ conv_b, const int* __restrict__ flags,
    float* __restrict__ out)
{
    int t = blockIdx.x * 256 + threadIdx.x;
    if (t >= N_NODES * DIM) return;
    int n = t >> 5;
    int d = t & 31;
    int ci = cntI[n];
    float c = ci < 1 ? 1.0f : (float)ci;
    out[t] = aggr[t] / c + ldf(conv_b, d, flags[7]);
}

extern "C" void kernel_launch(void* const* d_in, const int* in_sizes, int n_in,
                              void* d_out, int out_size, void* d_ws, size_t ws_size,
                              hipStream_t stream) {
    // inputs by size pattern, skipping scalar args:
    // 50000(x), 500000(ei), 250000(ea), 32, 32, 1024, 1024, 1024, 32
    const void* p[16];
    int np_ = 0;
    for (int i = 0; i < n_in && np_ < 16; ++i)
        if (in_sizes[i] != 1) p[np_++] = d_in[i];

    const void* x      = p[0];
    const int*  ei     = (const int*)p[1];
    const void* ea     = p[2];
    const void* node_W = p[3];
    const void* node_b = p[4];
    const void* l1_W   = p[5];
    const void* l1_b   = p[6];
    const void* root   = p[7];
    const void* conv_b = p[8];
    float* out = (float*)d_out;

    const int ND = N_NODES * DIM;
    float* ws = (float*)d_ws;
    int2*   eid      = (int2*)ws;                    // E int2, 2 MB
    float*  eaf      = (float*)(eid + N_EDGES);      // E floats, 1 MB
    int2*   packed   = (int2*)(eaf + N_EDGES);       // E int2, 2 MB
    float2* uv       = (float2*)(packed + N_EDGES);  // N*D float2, 12.8 MB
    float*  aggr     = (float*)(uv + ND);            // N*D floats, 6.4 MB
    int*    cntI     = (int*)(aggr + ND);            // N ints, zeroed
    int*    edge_cur = cntI + N_NODES;               // N ints, zeroed
    int*    flags    = edge_cur + N_NODES;           // 16 ints, zeroed
    int*    rowstart = flags + 16;                   // N ints
    int*    bsum     = rowstart + N_NODES;           // 64 ints

    (void)hipMemsetAsync(cntI, 0, (size_t)(2 * N_NODES + 16) * sizeof(int), stream);
    detect_kernel<<<9, 64, 0, stream>>>(x, ea, node_W, node_b, l1_W, l1_b,
                                        root, conv_b, ei, flags);
    count_kernel<<<(N_EDGES + 255) / 256, 256, 0, stream>>>(ei, ea, flags,
                                                            eid, eaf, cntI);
    scan_local_kernel<<<SCAN_NB, SCAN_B, 0, stream>>>(cntI, rowstart, bsum);
    scan_bsum_kernel<<<1, 64, 0, stream>>>(bsum);
    scan_add_kernel<<<SCAN_NB, SCAN_B, 0, stream>>>(rowstart, bsum);
    scatter_kernel<<<(N_EDGES + 255) / 256, 256, 0, stream>>>(eid, eaf, rowstart,
                                                              edge_cur, packed);

    const int gemm_blocks = (N_NODES + 7) / 8;   // 6250
    for (int layer = 0; layer < 3; ++layer) {
        gemm3_kernel<<<gemm_blocks, 256, 0, stream>>>(
            x, node_W, node_b, conv_b, l1_W, l1_b, root, flags, cntI,
            layer == 0 ? 0 : 1, uv, aggr);
        gather_kernel<<<gemm_blocks, 256, 0, stream>>>(packed, rowstart, cntI,
                                                       uv, aggr);
    }
    finalize_kernel<<<(ND + 255) / 256, 256, 0, stream>>>(aggr, cntI, conv_b,
                                                          flags, out);
}